// Round 6
// baseline (160.395 us; speedup 1.0000x reference)
//
#include <hip/hip_runtime.h>
#include <math.h>

#define HID    2048
#define NROW   16384
#define NCOL   168
#define BM     64      // rows per block
#define KSTEPS 64      // 2048 / 32
#define NELEM  2112    // 33 chunks * 64 lanes (16B each) per K-step
#define CPD    172     // sC row stride (f32)
#define NSLOT  16
#define NSTEP  8

typedef short short8 __attribute__((ext_vector_type(8)));
typedef float f32x4  __attribute__((ext_vector_type(4)));
typedef unsigned int u32x4 __attribute__((ext_vector_type(4)));

// [bf16(x1) : bf16(x0)] via v_perm_b32 (1 VALU op)
static __device__ __forceinline__ unsigned pack_hi(unsigned u0, unsigned u1) {
  return __builtin_amdgcn_perm(u1, u0, 0x07060302u);
}

// 3-way bf16 split (truncating; combined capture ~24 mantissa bits)
struct Planes { u32x4 p1, p2, p3; };
static __device__ __forceinline__ Planes split8(const float* x) {
  Planes P;
  #pragma unroll
  for (int q = 0; q < 4; ++q) {
    float x0 = x[2*q], x1 = x[2*q+1];
    unsigned u0 = __float_as_uint(x0), u1 = __float_as_uint(x1);
    P.p1[q] = pack_hi(u0, u1);
    float r0 = x0 - __uint_as_float(u0 & 0xFFFF0000u);
    float r1 = x1 - __uint_as_float(u1 & 0xFFFF0000u);
    unsigned v0 = __float_as_uint(r0), v1 = __float_as_uint(r1);
    P.p2[q] = pack_hi(v0, v1);
    float s0 = r0 - __uint_as_float(v0 & 0xFFFF0000u);
    float s1 = r1 - __uint_as_float(v1 & 0xFFFF0000u);
    P.p3[q] = pack_hi(__float_as_uint(s0), __float_as_uint(s1));
  }
  return P;
}

static __device__ __forceinline__ void loadA8(const float* p, float* x) {
  f32x4 a = *(const f32x4*)p;
  f32x4 b = *(const f32x4*)(p + 4);
  x[0]=a[0]; x[1]=a[1]; x[2]=a[2]; x[3]=a[3];
  x[4]=b[0]; x[5]=b[1]; x[6]=b[2]; x[7]=b[3];
}

// nontemporal (streaming) A load: keep the hidden stream out of L2 so wsB
// stays L2-resident — the round-4 bottleneck was B restaged from L3.
// NOTE: __builtin_nontemporal_load needs a clang ext_vector pointer, not
// HIP_vector_type (float4) — that was round 5's compile failure.
static __device__ __forceinline__ void loadA8_nt(const float* p, float* x) {
  f32x4 a = __builtin_nontemporal_load((const f32x4*)p);
  f32x4 b = __builtin_nontemporal_load((const f32x4*)(p + 4));
  x[0]=a[0]; x[1]=a[1]; x[2]=a[2]; x[3]=a[3];
  x[4]=b[0]; x[5]=b[1]; x[6]=b[2]; x[7]=b[3];
}

static __device__ __forceinline__ f32x4 mf(short8 a, short8 b, f32x4 c) {
  return __builtin_amdgcn_mfma_f32_16x16x32_bf16(a, b, c, 0, 0, 0);
}

// ---------------------------------------------------------------------------
// Prep: split W (concat 168 rows, 11 col-chunks of 16, zero-pad 168..175)
// into 3 bf16 planes in MFMA-B fragment-lane order.
// chunk(kidx, nt, pl): lane l holds B[k=kidx*32+(l>>4)*8+j][col=nt*16+(l&15)]
// ws element index = kidx*2112 + (nt*3+pl)*64 + l   (16B each)
// ---------------------------------------------------------------------------
__global__ void prep_b(const float* __restrict__ Wi, const float* __restrict__ Wo,
                       const float* __restrict__ Wg, u32x4* __restrict__ wsB) {
  int bid  = blockIdx.x;          // 64 * 11 = 704
  int kidx = bid / 11;
  int nt   = bid - kidx * 11;
  int l    = threadIdx.x;         // 64
  int col  = nt * 16 + (l & 15);
  int k0   = kidx * 32 + (l >> 4) * 8;

  float x[8];
  if (col < NCOL) {
    const float* wr = (col < 32)  ? (Wi + (size_t)col * HID)
                    : (col < 160) ? (Wo + (size_t)(col - 32) * HID)
                                  : (Wg + (size_t)(col - 160) * HID);
    loadA8(wr + k0, x);
  } else {
    #pragma unroll
    for (int i = 0; i < 8; ++i) x[i] = 0.f;
  }
  Planes P = split8(x);
  size_t base = (size_t)kidx * NELEM + (nt * 3) * 64 + l;
  wsB[base]       = P.p1;
  wsB[base + 64]  = P.p2;
  wsB[base + 128] = P.p3;
}

// ---------------------------------------------------------------------------
// Main: 256 blocks x 512 thr (8 waves, 2 wm x 4 wn), BM=64, 1 block/CU.
// NO LDS staging, NO K-loop barriers: each wave loads its own B fragments
// ws->VGPR (double-buffered, distance-1 prefetch); A via nontemporal loads.
// LDS holds only sC for the DAG epilogue.
// ---------------------------------------------------------------------------
__global__ __launch_bounds__(512, 2)
void dag_main(const float* __restrict__ hidden, const u32x4* __restrict__ wsB,
              const float* __restrict__ b_init, const float* __restrict__ b_op,
              const float* __restrict__ b_gate, float* __restrict__ out)
{
  __shared__ float sC[BM][CPD];   // 44032 B

  const int tid = threadIdx.x;
  const int l   = tid & 63;
  const int w   = tid >> 6;       // wave 0..7
  const int wm  = w >> 2;         // 0..1 : rows wm*32 + mt*16
  const int wn  = w & 3;          // 0..3 : cols wn*48 + j*16
  const int row0 = blockIdx.x * BM;
  const int r   = l & 15;
  const int kg  = l >> 4;

  // A: lane l covers rows row0 + wm*32 + mt*16 + r, k = t*32 + kg*8
  const float* ap0 = hidden + (size_t)(row0 + wm * 32 + r) * HID + kg * 8;
  const float* ap1 = ap0 + (size_t)16 * HID;

  // B fragments: chunk (wn*9 + j*3 + pl), element = t*NELEM + chunk*64 + l
  const u32x4* bbase = wsB + (size_t)(wn * 9) * 64 + l;

  f32x4 acc[2][3];
  const f32x4 zf = {0.f, 0.f, 0.f, 0.f};
  #pragma unroll
  for (int mt = 0; mt < 2; ++mt)
    #pragma unroll
    for (int j = 0; j < 3; ++j) acc[mt][j] = zf;

  float xc0[8], xc1[8], xn0[8], xn1[8];
  u32x4 bc[9], bn[9];

#define LOADB(dst_, t_) do {                                   \
    const u32x4* s_ = bbase + (size_t)NELEM * (t_);            \
    dst_[0] = s_[0 * 64]; dst_[1] = s_[1 * 64];                \
    dst_[2] = s_[2 * 64]; dst_[3] = s_[3 * 64];                \
    dst_[4] = s_[4 * 64]; dst_[5] = s_[5 * 64];                \
    if (wn != 3) {                                             \
      dst_[6] = s_[6 * 64]; dst_[7] = s_[7 * 64];              \
      dst_[8] = s_[8 * 64];                                    \
    }                                                          \
  } while (0)

#define STEP(bcur_, bnxt_, x0c_, x1c_, x0n_, x1n_, t_) do {                 \
    Planes PA0 = split8(x0c_);                                              \
    Planes PA1 = split8(x1c_);                                              \
    short8 a0p1 = __builtin_bit_cast(short8, PA0.p1);                       \
    short8 a0p2 = __builtin_bit_cast(short8, PA0.p2);                       \
    short8 a0p3 = __builtin_bit_cast(short8, PA0.p3);                       \
    short8 a1p1 = __builtin_bit_cast(short8, PA1.p1);                       \
    short8 a1p2 = __builtin_bit_cast(short8, PA1.p2);                       \
    short8 a1p3 = __builtin_bit_cast(short8, PA1.p3);                       \
    if ((t_) + 1 < KSTEPS) {                                                \
      loadA8_nt(ap0 + ((t_) + 1) * 32, x0n_);                               \
      loadA8_nt(ap1 + ((t_) + 1) * 32, x1n_);                               \
      LOADB(bnxt_, (t_) + 1);                                               \
    }                                                                       \
    __builtin_amdgcn_s_setprio(1);                                          \
    _Pragma("unroll")                                                       \
    for (int j = 0; j < 3; ++j) {                                           \
      if (wn == 3 && j == 2) continue;                                      \
      short8 b1 = __builtin_bit_cast(short8, bcur_[j * 3 + 0]);             \
      short8 b2 = __builtin_bit_cast(short8, bcur_[j * 3 + 1]);             \
      short8 b3 = __builtin_bit_cast(short8, bcur_[j * 3 + 2]);             \
      {                                                                     \
        f32x4 c = acc[0][j];                                                \
        c = mf(a0p1, b1, c); c = mf(a0p1, b2, c); c = mf(a0p2, b1, c);      \
        c = mf(a0p1, b3, c); c = mf(a0p2, b2, c); c = mf(a0p3, b1, c);      \
        acc[0][j] = c;                                                      \
      }                                                                     \
      {                                                                     \
        f32x4 c = acc[1][j];                                                \
        c = mf(a1p1, b1, c); c = mf(a1p1, b2, c); c = mf(a1p2, b1, c);      \
        c = mf(a1p1, b3, c); c = mf(a1p2, b2, c); c = mf(a1p3, b1, c);      \
        acc[1][j] = c;                                                      \
      }                                                                     \
    }                                                                       \
    __builtin_amdgcn_s_setprio(0);                                          \
  } while (0)

  // prologue: load step 0
  loadA8_nt(ap0, xc0);
  loadA8_nt(ap1, xc1);
  LOADB(bc, 0);

  for (int t = 0; t < KSTEPS; t += 2) {
    STEP(bc, bn, xc0, xc1, xn0, xn1, t);
    STEP(bn, bc, xn0, xn1, xc0, xc1, t + 1);
  }
#undef STEP
#undef LOADB

  // epilogue: acc -> sC
  #pragma unroll
  for (int mt = 0; mt < 2; ++mt) {
    #pragma unroll
    for (int j = 0; j < 3; ++j) {
      int col = wn * 48 + j * 16 + r;
      if (col < NCOL) {
        int row = wm * 32 + mt * 16 + kg * 4;
        sC[row + 0][col] = acc[mt][j][0];
        sC[row + 1][col] = acc[mt][j][1];
        sC[row + 2][col] = acc[mt][j][2];
        sC[row + 3][col] = acc[mt][j][3];
      }
    }
  }
  __syncthreads();

  // per-row sequential DAG: one lane per row (wave 0)
  if (tid < BM) {
    const int rr = tid;
    float Vm[NSLOT], Vs[NSLOT];
    #pragma unroll
    for (int i = 0; i < NSLOT; ++i) {
      float mv = sC[rr][i]      + b_init[i];
      float sv = sC[rr][16 + i] + b_init[16 + i];
      Vm[i] = fabsf(mv);
      Vs[i] = tanhf(sv);
    }
    float G[NSTEP];
    #pragma unroll
    for (int s = 0; s < NSTEP; ++s) {
      float gr = sC[rr][160 + s] + b_gate[s];
      G[s] = 1.0f / (1.0f + expf(-gr));
    }
    #pragma unroll
    for (int s = 0; s < NSTEP; ++s) {
      const float g = G[s];
      float R = 0.f, sp = 1.f;
      #pragma unroll
      for (int i = 0; i < NSLOT; ++i) {
        float Osi = (i < 8 + s) ? (sC[rr][32 + s * 16 + i] + b_op[s * 16 + i]) : 0.f;
        float sgn   = Vs[i] * Vm[i];
        float logm  = logf(fmaxf(Vm[i], 1e-12f));
        float mixed = logm * (1.f - g) + sgn * g;
        R  += Osi * mixed;
        sp *= Vs[i] * (fabsf(Osi) + 1.f);
      }
      float lin_sign = tanhf(R  / 1e-4f);
      float log_sign = tanhf(sp / 1e-4f);
      float vs_new = g * lin_sign + (1.f - g) * log_sign;
      float vm_new = g * fabsf(R) + (1.f - g) * expf(fminf(R, 23.026f));
      Vm[8 + s] = vm_new;
      Vs[8 + s] = vs_new;
    }
    out[row0 + rr] = Vs[NSLOT - 1] * Vm[NSLOT - 1];
  }
}

extern "C" void kernel_launch(void* const* d_in, const int* in_sizes, int n_in,
                              void* d_out, int out_size, void* d_ws, size_t ws_size,
                              hipStream_t stream) {
  (void)in_sizes; (void)n_in; (void)out_size; (void)ws_size;
  const float* hidden = (const float*)d_in[0];
  const float* W_init = (const float*)d_in[1];
  const float* b_init = (const float*)d_in[2];
  const float* W_op   = (const float*)d_in[3];
  const float* b_op   = (const float*)d_in[4];
  const float* W_gate = (const float*)d_in[5];
  const float* b_gate = (const float*)d_in[6];
  float* out = (float*)d_out;
  u32x4* wsB = (u32x4*)d_ws;      // 64 * 2112 * 16 B = 2.06 MiB

  prep_b<<<dim3(704), dim3(64), 0, stream>>>(W_init, W_op, W_gate, wsB);
  dag_main<<<dim3(NROW / BM), dim3(512), 0, stream>>>(hidden, wsB, b_init, b_op,
                                                      b_gate, out);
}

// Round 7
// 116.221 us; speedup vs baseline: 1.3801x; 1.3801x over previous
//
#include <hip/hip_runtime.h>
#include <math.h>

#define HID    2048
#define NROW   16384
#define NCOL   168
#define BM     32      // rows per block
#define KSTEPS 64      // 2048 / 32
#define NELEM  2112    // 33 chunks * 64 lanes (16B each) per K-step
#define CPD    172     // sC row stride (f32)
#define NSLOT  16
#define NSTEP  8

typedef short short8 __attribute__((ext_vector_type(8)));
typedef float f32x4  __attribute__((ext_vector_type(4)));
typedef unsigned int u32x4 __attribute__((ext_vector_type(4)));

// [bf16(x1) : bf16(x0)] via v_perm_b32 (1 VALU op)
static __device__ __forceinline__ unsigned pack_hi(unsigned u0, unsigned u1) {
  return __builtin_amdgcn_perm(u1, u0, 0x07060302u);
}

// 3-way bf16 split (truncating; combined capture ~24 mantissa bits)
struct Planes { u32x4 p1, p2, p3; };
static __device__ __forceinline__ Planes split8(const float* x) {
  Planes P;
  #pragma unroll
  for (int q = 0; q < 4; ++q) {
    float x0 = x[2*q], x1 = x[2*q+1];
    unsigned u0 = __float_as_uint(x0), u1 = __float_as_uint(x1);
    P.p1[q] = pack_hi(u0, u1);
    float r0 = x0 - __uint_as_float(u0 & 0xFFFF0000u);
    float r1 = x1 - __uint_as_float(u1 & 0xFFFF0000u);
    unsigned v0 = __float_as_uint(r0), v1 = __float_as_uint(r1);
    P.p2[q] = pack_hi(v0, v1);
    float s0 = r0 - __uint_as_float(v0 & 0xFFFF0000u);
    float s1 = r1 - __uint_as_float(v1 & 0xFFFF0000u);
    P.p3[q] = pack_hi(__float_as_uint(s0), __float_as_uint(s1));
  }
  return P;
}

static __device__ __forceinline__ void loadA8(const float* p, float* x) {
  f32x4 a = *(const f32x4*)p;
  f32x4 b = *(const f32x4*)(p + 4);
  x[0]=a[0]; x[1]=a[1]; x[2]=a[2]; x[3]=a[3];
  x[4]=b[0]; x[5]=b[1]; x[6]=b[2]; x[7]=b[3];
}

static __device__ __forceinline__ f32x4 mf(short8 a, short8 b, f32x4 c) {
  return __builtin_amdgcn_mfma_f32_16x16x32_bf16(a, b, c, 0, 0, 0);
}

// ---------------------------------------------------------------------------
// Prep: split W (concat 168 rows, 11 col-chunks of 16, zero-pad 168..175)
// into 3 bf16 planes in MFMA-B fragment-lane order.
// chunk(kidx, nt, pl): lane l holds B[k=kidx*32+(l>>4)*8+j][col=nt*16+(l&15)]
// ws element index = kidx*2112 + (nt*3+pl)*64 + l   (16B each)
// ---------------------------------------------------------------------------
__global__ void prep_b(const float* __restrict__ Wi, const float* __restrict__ Wo,
                       const float* __restrict__ Wg, u32x4* __restrict__ wsB) {
  int bid  = blockIdx.x;          // 64 * 11 = 704
  int kidx = bid / 11;
  int nt   = bid - kidx * 11;
  int l    = threadIdx.x;         // 64
  int col  = nt * 16 + (l & 15);
  int k0   = kidx * 32 + (l >> 4) * 8;

  float x[8];
  if (col < NCOL) {
    const float* wr = (col < 32)  ? (Wi + (size_t)col * HID)
                    : (col < 160) ? (Wo + (size_t)(col - 32) * HID)
                                  : (Wg + (size_t)(col - 160) * HID);
    loadA8(wr + k0, x);
  } else {
    #pragma unroll
    for (int i = 0; i < 8; ++i) x[i] = 0.f;
  }
  Planes P = split8(x);
  size_t base = (size_t)kidx * NELEM + (nt * 3) * 64 + l;
  wsB[base]       = P.p1;
  wsB[base + 64]  = P.p2;
  wsB[base + 128] = P.p3;
}

// ---------------------------------------------------------------------------
// Main: 512 blocks x 256 thr (4 waves, wave w = col-slice), BM=32.
// 3 blocks/CU (12 waves/CU) via launch_bounds(256,3) + LDS=22KB (sC only).
// No K-loop barriers; B ws->VGPR double-buffered with prefetch PINNED by
// sched_barrier(0) (round 6: compiler sank loads -> VGPR 84 -> no prefetch).
// ---------------------------------------------------------------------------
__global__ __launch_bounds__(256, 3)
void dag_main(const float* __restrict__ hidden, const u32x4* __restrict__ wsB,
              const float* __restrict__ b_init, const float* __restrict__ b_op,
              const float* __restrict__ b_gate, float* __restrict__ out)
{
  __shared__ float sC[BM][CPD];   // 22016 B

  const int tid = threadIdx.x;
  const int l   = tid & 63;
  const int w   = tid >> 6;       // wave 0..3 == col-slice wn
  const int row0 = blockIdx.x * BM;
  const int r   = l & 15;
  const int kg  = l >> 4;

  // A: lane l covers rows row0 + mt*16 + r, k = t*32 + kg*8
  const float* ap0 = hidden + (size_t)(row0 + r) * HID + kg * 8;
  const float* ap1 = ap0 + (size_t)16 * HID;

  // B fragments: chunk (w*9 + j*3 + pl), element = t*NELEM + chunk*64 + l
  const u32x4* bbase = wsB + (size_t)(w * 9) * 64 + l;

  f32x4 acc[2][3];
  const f32x4 zf = {0.f, 0.f, 0.f, 0.f};
  #pragma unroll
  for (int mt = 0; mt < 2; ++mt)
    #pragma unroll
    for (int j = 0; j < 3; ++j) acc[mt][j] = zf;

  float xc0[8], xc1[8], xn0[8], xn1[8];
  u32x4 bc[9], bn[9];

#define LOADB(dst_, t_) do {                                   \
    const u32x4* s_ = bbase + (size_t)NELEM * (t_);            \
    dst_[0] = s_[0 * 64]; dst_[1] = s_[1 * 64];                \
    dst_[2] = s_[2 * 64]; dst_[3] = s_[3 * 64];                \
    dst_[4] = s_[4 * 64]; dst_[5] = s_[5 * 64];                \
    if (w != 3) {                                              \
      dst_[6] = s_[6 * 64]; dst_[7] = s_[7 * 64];              \
      dst_[8] = s_[8 * 64];                                    \
    }                                                          \
  } while (0)

#define STEP(bcur_, bnxt_, x0c_, x1c_, x0n_, x1n_, t_) do {                 \
    Planes PA0 = split8(x0c_);                                              \
    Planes PA1 = split8(x1c_);                                              \
    short8 a0p1 = __builtin_bit_cast(short8, PA0.p1);                       \
    short8 a0p2 = __builtin_bit_cast(short8, PA0.p2);                       \
    short8 a0p3 = __builtin_bit_cast(short8, PA0.p3);                       \
    short8 a1p1 = __builtin_bit_cast(short8, PA1.p1);                       \
    short8 a1p2 = __builtin_bit_cast(short8, PA1.p2);                       \
    short8 a1p3 = __builtin_bit_cast(short8, PA1.p3);                       \
    if ((t_) + 1 < KSTEPS) {                                                \
      loadA8(ap0 + ((t_) + 1) * 32, x0n_);                                  \
      loadA8(ap1 + ((t_) + 1) * 32, x1n_);                                  \
      LOADB(bnxt_, (t_) + 1);                                               \
    }                                                                       \
    /* pin: next-step loads must be ISSUED before the MFMA cluster */       \
    __builtin_amdgcn_sched_barrier(0);                                      \
    __builtin_amdgcn_s_setprio(1);                                          \
    _Pragma("unroll")                                                       \
    for (int j = 0; j < 3; ++j) {                                           \
      if (w == 3 && j == 2) continue;                                       \
      short8 b1 = __builtin_bit_cast(short8, bcur_[j * 3 + 0]);             \
      short8 b2 = __builtin_bit_cast(short8, bcur_[j * 3 + 1]);             \
      short8 b3 = __builtin_bit_cast(short8, bcur_[j * 3 + 2]);             \
      {                                                                     \
        f32x4 c = acc[0][j];                                                \
        c = mf(a0p1, b1, c); c = mf(a0p1, b2, c); c = mf(a0p2, b1, c);      \
        c = mf(a0p1, b3, c); c = mf(a0p2, b2, c); c = mf(a0p3, b1, c);      \
        acc[0][j] = c;                                                      \
      }                                                                     \
      {                                                                     \
        f32x4 c = acc[1][j];                                                \
        c = mf(a1p1, b1, c); c = mf(a1p1, b2, c); c = mf(a1p2, b1, c);      \
        c = mf(a1p1, b3, c); c = mf(a1p2, b2, c); c = mf(a1p3, b1, c);      \
        acc[1][j] = c;                                                      \
      }                                                                     \
    }                                                                       \
    __builtin_amdgcn_s_setprio(0);                                          \
  } while (0)

  // prologue: load step 0
  loadA8(ap0, xc0);
  loadA8(ap1, xc1);
  LOADB(bc, 0);

  for (int t = 0; t < KSTEPS; t += 2) {
    STEP(bc, bn, xc0, xc1, xn0, xn1, t);
    STEP(bn, bc, xn0, xn1, xc0, xc1, t + 1);
  }
#undef STEP
#undef LOADB

  // epilogue: acc -> sC
  #pragma unroll
  for (int mt = 0; mt < 2; ++mt) {
    #pragma unroll
    for (int j = 0; j < 3; ++j) {
      int col = w * 48 + j * 16 + r;
      if (col < NCOL) {
        int row = mt * 16 + kg * 4;
        sC[row + 0][col] = acc[mt][j][0];
        sC[row + 1][col] = acc[mt][j][1];
        sC[row + 2][col] = acc[mt][j][2];
        sC[row + 3][col] = acc[mt][j][3];
      }
    }
  }
  __syncthreads();

  // per-row sequential DAG: one lane per row (wave 0)
  if (tid < BM) {
    const int rr = tid;
    float Vm[NSLOT], Vs[NSLOT];
    #pragma unroll
    for (int i = 0; i < NSLOT; ++i) {
      float mv = sC[rr][i]      + b_init[i];
      float sv = sC[rr][16 + i] + b_init[16 + i];
      Vm[i] = fabsf(mv);
      Vs[i] = tanhf(sv);
    }
    float G[NSTEP];
    #pragma unroll
    for (int s = 0; s < NSTEP; ++s) {
      float gr = sC[rr][160 + s] + b_gate[s];
      G[s] = 1.0f / (1.0f + expf(-gr));
    }
    #pragma unroll
    for (int s = 0; s < NSTEP; ++s) {
      const float g = G[s];
      float R = 0.f, sp = 1.f;
      #pragma unroll
      for (int i = 0; i < NSLOT; ++i) {
        float Osi = (i < 8 + s) ? (sC[rr][32 + s * 16 + i] + b_op[s * 16 + i]) : 0.f;
        float sgn   = Vs[i] * Vm[i];
        float logm  = logf(fmaxf(Vm[i], 1e-12f));
        float mixed = logm * (1.f - g) + sgn * g;
        R  += Osi * mixed;
        sp *= Vs[i] * (fabsf(Osi) + 1.f);
      }
      float lin_sign = tanhf(R  / 1e-4f);
      float log_sign = tanhf(sp / 1e-4f);
      float vs_new = g * lin_sign + (1.f - g) * log_sign;
      float vm_new = g * fabsf(R) + (1.f - g) * expf(fminf(R, 23.026f));
      Vm[8 + s] = vm_new;
      Vs[8 + s] = vs_new;
    }
    out[row0 + rr] = Vs[NSLOT - 1] * Vm[NSLOT - 1];
  }
}

extern "C" void kernel_launch(void* const* d_in, const int* in_sizes, int n_in,
                              void* d_out, int out_size, void* d_ws, size_t ws_size,
                              hipStream_t stream) {
  (void)in_sizes; (void)n_in; (void)out_size; (void)ws_size;
  const float* hidden = (const float*)d_in[0];
  const float* W_init = (const float*)d_in[1];
  const float* b_init = (const float*)d_in[2];
  const float* W_op   = (const float*)d_in[3];
  const float* b_op   = (const float*)d_in[4];
  const float* W_gate = (const float*)d_in[5];
  const float* b_gate = (const float*)d_in[6];
  float* out = (float*)d_out;
  u32x4* wsB = (u32x4*)d_ws;      // 64 * 2112 * 16 B = 2.06 MiB

  prep_b<<<dim3(704), dim3(64), 0, stream>>>(W_init, W_op, W_gate, wsB);
  dag_main<<<dim3(NROW / BM), dim3(256), 0, stream>>>(hidden, wsB, b_init, b_op,
                                                      b_gate, out);
}

// Round 9
// 115.300 us; speedup vs baseline: 1.3911x; 1.0080x over previous
//
#include <hip/hip_runtime.h>
#include <math.h>

#define HID    2048
#define NROW   16384
#define NCOL   168
#define BM     32      // rows per block
#define KSTEPS 64      // 2048 / 32
#define NELEM  2112    // 33 chunks * 64 lanes (16B each) per K-step
#define BUFB   33792   // 33 KB per LDS B buffer
#define CPD    172     // sC row stride (f32)
#define NSLOT  16
#define NSTEP  8

typedef short short8 __attribute__((ext_vector_type(8)));
typedef float f32x4  __attribute__((ext_vector_type(4)));
typedef unsigned int u32x4 __attribute__((ext_vector_type(4)));

// counted waits — the T4 primitive. volatile + memory clobber orders all
// memory ops (loads/DMA/ds_read) across these; reg-only ops may drift (ok).
static __device__ __forceinline__ void wait_vm13() {
  asm volatile("s_waitcnt vmcnt(13)" ::: "memory");
}
static __device__ __forceinline__ void wait_vm0() {
  asm volatile("s_waitcnt vmcnt(0)" ::: "memory");
}
static __device__ __forceinline__ void wait_lgkm0() {
  asm volatile("s_waitcnt lgkmcnt(0)" ::: "memory");
}

// [bf16(x1) : bf16(x0)] via v_perm_b32 (1 VALU op)
static __device__ __forceinline__ unsigned pack_hi(unsigned u0, unsigned u1) {
  return __builtin_amdgcn_perm(u1, u0, 0x07060302u);
}

// 3-way bf16 split (truncating; combined capture ~24 mantissa bits)
struct Planes { u32x4 p1, p2, p3; };
static __device__ __forceinline__ Planes split8(const float* x) {
  Planes P;
  #pragma unroll
  for (int q = 0; q < 4; ++q) {
    float x0 = x[2*q], x1 = x[2*q+1];
    unsigned u0 = __float_as_uint(x0), u1 = __float_as_uint(x1);
    P.p1[q] = pack_hi(u0, u1);
    float r0 = x0 - __uint_as_float(u0 & 0xFFFF0000u);
    float r1 = x1 - __uint_as_float(u1 & 0xFFFF0000u);
    unsigned v0 = __float_as_uint(r0), v1 = __float_as_uint(r1);
    P.p2[q] = pack_hi(v0, v1);
    float s0 = r0 - __uint_as_float(v0 & 0xFFFF0000u);
    float s1 = r1 - __uint_as_float(v1 & 0xFFFF0000u);
    P.p3[q] = pack_hi(__float_as_uint(s0), __float_as_uint(s1));
  }
  return P;
}

static __device__ __forceinline__ void loadA8(const float* p, float* x) {
  f32x4 a = *(const f32x4*)p;
  f32x4 b = *(const f32x4*)(p + 4);
  x[0]=a[0]; x[1]=a[1]; x[2]=a[2]; x[3]=a[3];
  x[4]=b[0]; x[5]=b[1]; x[6]=b[2]; x[7]=b[3];
}

static __device__ __forceinline__ f32x4 mf(short8 a, short8 b, f32x4 c) {
  return __builtin_amdgcn_mfma_f32_16x16x32_bf16(a, b, c, 0, 0, 0);
}

// async global->LDS, 16B per lane; LDS dest = wave-uniform base + lane*16
static __device__ __forceinline__ void gld_lds16(const void* g, void* l) {
  __builtin_amdgcn_global_load_lds(
      (const __attribute__((address_space(1))) unsigned int*)g,
      (__attribute__((address_space(3))) unsigned int*)l, 16, 0, 0);
}

// ---------------------------------------------------------------------------
// Prep: split W (concat 168 rows, 11 col-chunks of 16, zero-pad 168..175)
// into 3 bf16 planes in MFMA-B fragment-lane order.
// chunk(kidx, nt, pl): lane l holds B[k=kidx*32+(l>>4)*8+j][col=nt*16+(l&15)]
// ws element index = kidx*2112 + (nt*3+pl)*64 + l   (16B each)
// ---------------------------------------------------------------------------
__global__ void prep_b(const float* __restrict__ Wi, const float* __restrict__ Wo,
                       const float* __restrict__ Wg, u32x4* __restrict__ wsB) {
  int bid  = blockIdx.x;          // 64 * 11 = 704
  int kidx = bid / 11;
  int nt   = bid - kidx * 11;
  int l    = threadIdx.x;         // 64
  int col  = nt * 16 + (l & 15);
  int k0   = kidx * 32 + (l >> 4) * 8;

  float x[8];
  if (col < NCOL) {
    const float* wr = (col < 32)  ? (Wi + (size_t)col * HID)
                    : (col < 160) ? (Wo + (size_t)(col - 32) * HID)
                                  : (Wg + (size_t)(col - 160) * HID);
    loadA8(wr + k0, x);
  } else {
    #pragma unroll
    for (int i = 0; i < 8; ++i) x[i] = 0.f;
  }
  Planes P = split8(x);
  size_t base = (size_t)kidx * NELEM + (nt * 3) * 64 + l;
  wsB[base]       = P.p1;
  wsB[base + 64]  = P.p2;
  wsB[base + 128] = P.p3;
}

// ---------------------------------------------------------------------------
// Main: 512 blocks x 256 thr (4 waves), BM=32, 2 blocks/CU.
// ZERO K-loop barriers: each wave stages (via global_load_lds DMA) exactly
// the 9 B chunks it reads -> no cross-wave deps. Counted vmcnt(13) per step
// keeps next-step DMA + A loads in flight (B/A prefetch distance 2).
//
// Ledger (per wave): every body issues exactly 13 VMEM ops (9 B-DMA + 4 A).
// Body t entry in-flight = {B(t):9, A(t):4, B(t+1):9, A(t+1):4} = 26;
// vmcnt(13) drains the oldest 13 = B(t)+A(t). Bodies 0..61 issue t+2;
// bodies 62 (vmcnt(13)) and 63 (vmcnt(0)) issue nothing.
// ROUND-8 BUG FIXED: loop guard (t<60) starved bodies 62/63 of B/A(62,63).
// ---------------------------------------------------------------------------
__global__ __launch_bounds__(256, 2)
void dag_main(const float* __restrict__ hidden, const u32x4* __restrict__ wsB,
              const float* __restrict__ b_init, const float* __restrict__ b_op,
              const float* __restrict__ b_gate, float* __restrict__ out)
{
  __shared__ __align__(16) char smem[2 * BUFB];   // 67584 B (sC overlays)

  const int tid = threadIdx.x;
  const int l   = tid & 63;
  const int w   = tid >> 6;       // wave 0..3 == col-slice
  const int row0 = blockIdx.x * BM;
  const int r   = l & 15;
  const int kg  = l >> 4;

  // A: lane l covers rows row0 + mt*16 + r, k = t*32 + kg*8
  const float* ap0 = hidden + (size_t)(row0 + r) * HID + kg * 8;
  const float* ap1 = ap0 + (size_t)16 * HID;

  // per-wave chunk ownership: stage set == read set (chunks 9w .. 9w+8).
  // wave 3 reads only 6 (cols 176.. are pad); it re-stages chunks 27..29
  // idempotently so every wave issues exactly 9 DMA ops (uniform ledger).
  const u32x4* gsrc[9];
  char* ldst[9];
  #pragma unroll
  for (int i = 0; i < 9; ++i) {
    int ii = (w == 3 && i >= 6) ? i - 6 : i;
    int c  = 9 * w + ii;
    gsrc[i] = wsB + (size_t)c * 64 + l;      // per-lane global source
    ldst[i] = smem + c * 1024;               // wave-uniform LDS dest
  }
  // B fragment read base: chunk (9w + j*3 + pl), byte = chunk*1024 + l*16
  const char* brd0 = smem + (size_t)(9 * w) * 1024 + (size_t)l * 16;

  f32x4 acc[2][3];
  const f32x4 zf = {0.f, 0.f, 0.f, 0.f};
  #pragma unroll
  for (int mt = 0; mt < 2; ++mt)
    #pragma unroll
    for (int j = 0; j < 3; ++j) acc[mt][j] = zf;

  float xa0[8], xa1[8], xb0[8], xb1[8];

#define STAGE(t_, sel_) do {                                                \
    _Pragma("unroll")                                                       \
    for (int i = 0; i < 9; ++i)                                             \
      gld_lds16(gsrc[i] + (size_t)NELEM * (t_), ldst[i] + (sel_) * BUFB);   \
  } while (0)

  // BODY(t): wait(B(t),A(t) done) -> ds_read B(t) -> lgkm0 ->
  //          issue B(t+2) into same (now-consumed) buffer + A(t+2) ->
  //          split A(t) -> MFMA.
#define BODY(t_, p_, xc0_, xc1_, ISSUE_, LAST_) do {                        \
    if (LAST_) wait_vm0(); else wait_vm13();                                \
    __builtin_amdgcn_sched_barrier(0);                                      \
    const char* bb = brd0 + (p_) * BUFB;                                    \
    short8 bf[9];                                                           \
    _Pragma("unroll")                                                       \
    for (int i = 0; i < 9; ++i)                                             \
      if (w != 3 || i < 6) bf[i] = *(const short8*)(bb + i * 1024);         \
    wait_lgkm0();   /* reads complete before DMA re-targets this buffer */  \
    __builtin_amdgcn_sched_barrier(0);                                      \
    if (ISSUE_) STAGE((t_) + 2, (p_));                                      \
    Planes PA0 = split8(xc0_);                                              \
    Planes PA1 = split8(xc1_);                                              \
    if (ISSUE_) {                                                           \
      loadA8(ap0 + ((t_) + 2) * 32, xc0_);                                  \
      loadA8(ap1 + ((t_) + 2) * 32, xc1_);                                  \
    }                                                                       \
    short8 a0p1 = __builtin_bit_cast(short8, PA0.p1);                       \
    short8 a0p2 = __builtin_bit_cast(short8, PA0.p2);                       \
    short8 a0p3 = __builtin_bit_cast(short8, PA0.p3);                       \
    short8 a1p1 = __builtin_bit_cast(short8, PA1.p1);                       \
    short8 a1p2 = __builtin_bit_cast(short8, PA1.p2);                       \
    short8 a1p3 = __builtin_bit_cast(short8, PA1.p3);                       \
    __builtin_amdgcn_s_setprio(1);                                          \
    _Pragma("unroll")                                                       \
    for (int j = 0; j < 3; ++j) {                                           \
      if (w == 3 && j == 2) continue;                                       \
      short8 b1 = bf[j * 3 + 0];                                            \
      short8 b2 = bf[j * 3 + 1];                                            \
      short8 b3 = bf[j * 3 + 2];                                            \
      {                                                                     \
        f32x4 c = acc[0][j];                                                \
        c = mf(a0p1, b1, c); c = mf(a0p1, b2, c); c = mf(a0p2, b1, c);      \
        c = mf(a0p1, b3, c); c = mf(a0p2, b2, c); c = mf(a0p3, b1, c);      \
        acc[0][j] = c;                                                      \
      }                                                                     \
      {                                                                     \
        f32x4 c = acc[1][j];                                                \
        c = mf(a1p1, b1, c); c = mf(a1p1, b2, c); c = mf(a1p2, b1, c);      \
        c = mf(a1p1, b3, c); c = mf(a1p2, b2, c); c = mf(a1p3, b1, c);      \
        acc[1][j] = c;                                                      \
      }                                                                     \
    }                                                                       \
    __builtin_amdgcn_s_setprio(0);                                          \
  } while (0)

  // prologue: queue = [B(0):9, A(0):4, B(1):9, A(1):4] = 26 in flight
  STAGE(0, 0);
  loadA8(ap0,      xa0);
  loadA8(ap1,      xa1);
  STAGE(1, 1);
  loadA8(ap0 + 32, xb0);
  loadA8(ap1 + 32, xb1);

  // bodies 0..61 all issue t+2 (last issues: body 60 -> B/A(62), 61 -> B/A(63))
  for (int t = 0; t < 62; t += 2) {
    BODY(t,     0, xa0, xa1, true, false);
    BODY(t + 1, 1, xb0, xb1, true, false);
  }
  // tail: nothing left to issue; 62 waits its 13, 63 drains to zero
  BODY(62, 0, xa0, xa1, false, false);
  BODY(63, 1, xb0, xb1, false, true);
#undef BODY
#undef STAGE

  // epilogue: acc -> sC (overlays LDS; all waves' reads/DMA drained)
  __syncthreads();
  float (*sC)[CPD] = (float(*)[CPD])smem;
  #pragma unroll
  for (int mt = 0; mt < 2; ++mt) {
    #pragma unroll
    for (int j = 0; j < 3; ++j) {
      int col = w * 48 + j * 16 + r;
      if (col < NCOL) {
        int row = mt * 16 + kg * 4;
        sC[row + 0][col] = acc[mt][j][0];
        sC[row + 1][col] = acc[mt][j][1];
        sC[row + 2][col] = acc[mt][j][2];
        sC[row + 3][col] = acc[mt][j][3];
      }
    }
  }
  __syncthreads();

  // per-row sequential DAG: one lane per row (wave 0)
  if (tid < BM) {
    const int rr = tid;
    float Vm[NSLOT], Vs[NSLOT];
    #pragma unroll
    for (int i = 0; i < NSLOT; ++i) {
      float mv = sC[rr][i]      + b_init[i];
      float sv = sC[rr][16 + i] + b_init[16 + i];
      Vm[i] = fabsf(mv);
      Vs[i] = tanhf(sv);
    }
    float G[NSTEP];
    #pragma unroll
    for (int s = 0; s < NSTEP; ++s) {
      float gr = sC[rr][160 + s] + b_gate[s];
      G[s] = 1.0f / (1.0f + expf(-gr));
    }
    #pragma unroll
    for (int s = 0; s < NSTEP; ++s) {
      const float g = G[s];
      float R = 0.f, sp = 1.f;
      #pragma unroll
      for (int i = 0; i < NSLOT; ++i) {
        float Osi = (i < 8 + s) ? (sC[rr][32 + s * 16 + i] + b_op[s * 16 + i]) : 0.f;
        float sgn   = Vs[i] * Vm[i];
        float logm  = logf(fmaxf(Vm[i], 1e-12f));
        float mixed = logm * (1.f - g) + sgn * g;
        R  += Osi * mixed;
        sp *= Vs[i] * (fabsf(Osi) + 1.f);
      }
      float lin_sign = tanhf(R  / 1e-4f);
      float log_sign = tanhf(sp / 1e-4f);
      float vs_new = g * lin_sign + (1.f - g) * log_sign;
      float vm_new = g * fabsf(R) + (1.f - g) * expf(fminf(R, 23.026f));
      Vm[8 + s] = vm_new;
      Vs[8 + s] = vs_new;
    }
    out[row0 + rr] = Vs[NSLOT - 1] * Vm[NSLOT - 1];
  }
}

extern "C" void kernel_launch(void* const* d_in, const int* in_sizes, int n_in,
                              void* d_out, int out_size, void* d_ws, size_t ws_size,
                              hipStream_t stream) {
  (void)in_sizes; (void)n_in; (void)out_size; (void)ws_size;
  const float* hidden = (const float*)d_in[0];
  const float* W_init = (const float*)d_in[1];
  const float* b_init = (const float*)d_in[2];
  const float* W_op   = (const float*)d_in[3];
  const float* b_op   = (const float*)d_in[4];
  const float* W_gate = (const float*)d_in[5];
  const float* b_gate = (const float*)d_in[6];
  float* out = (float*)d_out;
  u32x4* wsB = (u32x4*)d_ws;      // 64 * 2112 * 16 B = 2.06 MiB

  prep_b<<<dim3(704), dim3(64), 0, stream>>>(W_init, W_op, W_gate, wsB);
  dag_main<<<dim3(NROW / BM), dim3(256), 0, stream>>>(hidden, wsB, b_init, b_op,
                                                      b_gate, out);
}

// Round 11
// 100.499 us; speedup vs baseline: 1.5960x; 1.1473x over previous
//
#include <hip/hip_runtime.h>
#include <math.h>

#define HID    2048
#define NROW   16384
#define NCOL   168
#define BM     64      // rows per block
#define KSTEPS 64      // 2048 / 32
#define NELEM  2112    // 33 chunks * 64 lanes (16B each) per K-step
#define BUFB   33792   // 33 KB per LDS B buffer (x3)
#define CPD    172     // sC row stride (f32)
#define NSLOT  16
#define NSTEP  8

typedef short short8 __attribute__((ext_vector_type(8)));
typedef float f32x4  __attribute__((ext_vector_type(4)));
typedef unsigned int u32x4 __attribute__((ext_vector_type(4)));

// counted waits — T4 primitive. volatile + memory clobber pins memory ops.
static __device__ __forceinline__ void wait_vm9() {
  asm volatile("s_waitcnt vmcnt(9)" ::: "memory");
}
static __device__ __forceinline__ void wait_vm0() {
  asm volatile("s_waitcnt vmcnt(0)" ::: "memory");
}

// [bf16(x1) : bf16(x0)] via v_perm_b32 (1 VALU op)
static __device__ __forceinline__ unsigned pack_hi(unsigned u0, unsigned u1) {
  return __builtin_amdgcn_perm(u1, u0, 0x07060302u);
}

// 3-way bf16 split (truncating; captures ~24 mantissa bits across planes)
struct Planes { u32x4 p1, p2, p3; };
static __device__ __forceinline__ Planes split8(const float* x) {
  Planes P;
  #pragma unroll
  for (int q = 0; q < 4; ++q) {
    float x0 = x[2*q], x1 = x[2*q+1];
    unsigned u0 = __float_as_uint(x0), u1 = __float_as_uint(x1);
    P.p1[q] = pack_hi(u0, u1);
    float r0 = x0 - __uint_as_float(u0 & 0xFFFF0000u);
    float r1 = x1 - __uint_as_float(u1 & 0xFFFF0000u);
    unsigned v0 = __float_as_uint(r0), v1 = __float_as_uint(r1);
    P.p2[q] = pack_hi(v0, v1);
    float s0 = r0 - __uint_as_float(v0 & 0xFFFF0000u);
    float s1 = r1 - __uint_as_float(v1 & 0xFFFF0000u);
    P.p3[q] = pack_hi(__float_as_uint(s0), __float_as_uint(s1));
  }
  return P;
}

static __device__ __forceinline__ void loadA8(const float* p, float* x) {
  f32x4 a = *(const f32x4*)p;
  f32x4 b = *(const f32x4*)(p + 4);
  x[0]=a[0]; x[1]=a[1]; x[2]=a[2]; x[3]=a[3];
  x[4]=b[0]; x[5]=b[1]; x[6]=b[2]; x[7]=b[3];
}

static __device__ __forceinline__ f32x4 mf(short8 a, short8 b, f32x4 c) {
  return __builtin_amdgcn_mfma_f32_16x16x32_bf16(a, b, c, 0, 0, 0);
}

// async global->LDS, 16B per lane; LDS dest = wave-uniform base + lane*16
static __device__ __forceinline__ void gld_lds16(const void* g, void* l) {
  __builtin_amdgcn_global_load_lds(
      (const __attribute__((address_space(1))) unsigned int*)g,
      (__attribute__((address_space(3))) unsigned int*)l, 16, 0, 0);
}

// ---------------------------------------------------------------------------
// Prep: split W (concat 168 rows, 11 col-chunks of 16, zero-pad 168..175)
// into 3 bf16 planes in MFMA-B fragment-lane order.
// chunk(kidx, nt, pl): lane l holds B[k=kidx*32+(l>>4)*8+j][col=nt*16+(l&15)]
// ws element index = kidx*2112 + (nt*3+pl)*64 + l   (16B each)
// ---------------------------------------------------------------------------
__global__ void prep_b(const float* __restrict__ Wi, const float* __restrict__ Wo,
                       const float* __restrict__ Wg, u32x4* __restrict__ wsB) {
  int bid  = blockIdx.x;          // 64 * 11 = 704
  int kidx = bid / 11;
  int nt   = bid - kidx * 11;
  int l    = threadIdx.x;         // 64
  int col  = nt * 16 + (l & 15);
  int k0   = kidx * 32 + (l >> 4) * 8;

  float x[8];
  if (col < NCOL) {
    const float* wr = (col < 32)  ? (Wi + (size_t)col * HID)
                    : (col < 160) ? (Wo + (size_t)(col - 32) * HID)
                                  : (Wg + (size_t)(col - 160) * HID);
    loadA8(wr + k0, x);
  } else {
    #pragma unroll
    for (int i = 0; i < 8; ++i) x[i] = 0.f;
  }
  Planes P = split8(x);
  size_t base = (size_t)kidx * NELEM + (nt * 3) * 64 + l;
  wsB[base]       = P.p1;
  wsB[base + 64]  = P.p2;
  wsB[base + 128] = P.p3;
}

// ---------------------------------------------------------------------------
// Main: 256 blocks x 512 thr (8 waves: 2 wm x 4 wn), BM=64, 1 block/CU.
// Triple-buffered shared B staging, ONE raw s_barrier per body (no vmcnt
// drain), counted vmcnt(9). The wm-pair splits its slice's 9 chunks 5/5
// (1-chunk overlap, same step + same bytes under barrier lock => safe).
//
// Safety proof per body t (after barrier):
//   (a) every wave passed its own vmcnt(9) => all of B(t) landed in buf[t%3];
//   (b) every wave finished body t-1 (its ds_reads complete before its MFMAs
//       which precede barrier arrival) => buf[(t+2)%3] (holding B(t-1)) is
//       no longer being read => safe DMA target for B(t+2).
// Ledger: 9 VMEM/body/wave (5 B-DMA + 4 A); steady vmcnt(9); tail 9 -> 0.
// ---------------------------------------------------------------------------
__global__ __launch_bounds__(512, 2)
void dag_main(const float* __restrict__ hidden, const u32x4* __restrict__ wsB,
              const float* __restrict__ b_init, const float* __restrict__ b_op,
              const float* __restrict__ b_gate, float* __restrict__ out)
{
  __shared__ __align__(16) char smem[3 * BUFB];   // 101376 B (sC overlays)

  const int tid = threadIdx.x;
  const int l   = tid & 63;
  const int w   = tid >> 6;       // wave 0..7
  const int wn  = w & 3;          // col-slice: cols wn*48 + j*16
  const int wm  = w >> 2;         // row-band:  rows wm*32 + mt*16
  const int row0 = blockIdx.x * BM;
  const int r   = l & 15;
  const int kg  = l >> 4;

  // A: lane l covers rows row0 + wm*32 + mt*16 + r, k = t*32 + kg*8
  const float* ap0 = hidden + (size_t)(row0 + wm * 32 + r) * HID + kg * 8;
  const float* ap1 = ap0 + (size_t)16 * HID;

  // staging split: wm=0 stages chunks cb..cb+4 = 9wn..9wn+4;
  // wm=1 stages 9wn+4..9wn+8 (wn<3) or 28..32 (wn==3, 6 real chunks).
  const int cb = 9 * wn + (wm ? ((wn == 3) ? 1 : 4) : 0);
  const u32x4* gsrc[5];
  char* ldst[5];
  #pragma unroll
  for (int i = 0; i < 5; ++i) {
    gsrc[i] = wsB + (size_t)(cb + i) * 64 + l;   // per-lane global source
    ldst[i] = smem + (cb + i) * 1024;            // wave-uniform LDS dest
  }
  // B fragment read base: chunk (9wn + j*3 + pl), byte = chunk*1024 + l*16
  const char* brd0 = smem + (size_t)(9 * wn) * 1024 + (size_t)l * 16;

  f32x4 acc[2][3];
  const f32x4 zf = {0.f, 0.f, 0.f, 0.f};
  #pragma unroll
  for (int mt = 0; mt < 2; ++mt)
    #pragma unroll
    for (int j = 0; j < 3; ++j) acc[mt][j] = zf;

  float xa0[8], xa1[8], xb0[8], xb1[8];

#define STAGE(t_, sel_) do {                                                \
    _Pragma("unroll")                                                       \
    for (int i = 0; i < 5; ++i)                                             \
      gld_lds16(gsrc[i] + (size_t)NELEM * (t_), ldst[i] + (sel_) * BUFB);   \
  } while (0)

  // BODY(t): wait own 9 -> barrier -> ds_read B(t) from buf[p] ->
  //          DMA B(t+2) into buf[(p+2)%3] -> split A(t) -> load A(t+2)
  //          -> MFMA (compiler inserts fine-grained lgkmcnt for bf).
#define BODY(t_, p_, xc0_, xc1_, ISSUE_, LAST_) do {                        \
    if (LAST_) wait_vm0(); else wait_vm9();                                 \
    __builtin_amdgcn_sched_barrier(0);                                      \
    __builtin_amdgcn_s_barrier();                                           \
    __builtin_amdgcn_sched_barrier(0);                                      \
    const char* bb = brd0 + (p_) * BUFB;                                    \
    short8 bf[9];                                                           \
    _Pragma("unroll")                                                       \
    for (int i = 0; i < 9; ++i)                                             \
      if (wn != 3 || i < 6) bf[i] = *(const short8*)(bb + i * 1024);        \
    if (ISSUE_) STAGE((t_) + 2, ((p_) + 2) % 3);                            \
    Planes PA0 = split8(xc0_);                                              \
    Planes PA1 = split8(xc1_);                                              \
    if (ISSUE_) {                                                           \
      loadA8(ap0 + ((t_) + 2) * 32, xc0_);                                  \
      loadA8(ap1 + ((t_) + 2) * 32, xc1_);                                  \
    }                                                                       \
    short8 a0p1 = __builtin_bit_cast(short8, PA0.p1);                       \
    short8 a0p2 = __builtin_bit_cast(short8, PA0.p2);                       \
    short8 a0p3 = __builtin_bit_cast(short8, PA0.p3);                       \
    short8 a1p1 = __builtin_bit_cast(short8, PA1.p1);                       \
    short8 a1p2 = __builtin_bit_cast(short8, PA1.p2);                       \
    short8 a1p3 = __builtin_bit_cast(short8, PA1.p3);                       \
    __builtin_amdgcn_s_setprio(1);                                          \
    _Pragma("unroll")                                                       \
    for (int j = 0; j < 3; ++j) {                                           \
      if (wn == 3 && j == 2) continue;                                      \
      short8 b1 = bf[j * 3 + 0];                                            \
      short8 b2 = bf[j * 3 + 1];                                            \
      short8 b3 = bf[j * 3 + 2];                                            \
      {                                                                     \
        f32x4 c = acc[0][j];                                                \
        c = mf(a0p1, b1, c); c = mf(a0p1, b2, c); c = mf(a0p2, b1, c);      \
        c = mf(a0p1, b3, c); c = mf(a0p2, b2, c); c = mf(a0p3, b1, c);      \
        acc[0][j] = c;                                                      \
      }                                                                     \
      {                                                                     \
        f32x4 c = acc[1][j];                                                \
        c = mf(a1p1, b1, c); c = mf(a1p1, b2, c); c = mf(a1p2, b1, c);      \
        c = mf(a1p1, b3, c); c = mf(a1p2, b2, c); c = mf(a1p3, b1, c);      \
        acc[1][j] = c;                                                      \
      }                                                                     \
    }                                                                       \
    __builtin_amdgcn_s_setprio(0);                                          \
  } while (0)

  // prologue: [B(0):5, A(0):4] then [B(1):5, A(1):4] = 18 in flight
  STAGE(0, 0);
  loadA8(ap0,      xa0);
  loadA8(ap1,      xa1);
  STAGE(1, 1);
  loadA8(ap0 + 32, xb0);
  loadA8(ap1 + 32, xb1);

  // bodies 0..61 issue t+2; buffer cycle period 3, A-reg period 2 -> unroll 6
  for (int t = 0; t < 60; t += 6) {
    BODY(t + 0, 0, xa0, xa1, true, false);
    BODY(t + 1, 1, xb0, xb1, true, false);
    BODY(t + 2, 2, xa0, xa1, true, false);
    BODY(t + 3, 0, xb0, xb1, true, false);
    BODY(t + 4, 1, xa0, xa1, true, false);
    BODY(t + 5, 2, xb0, xb1, true, false);
  }
  BODY(60, 0, xa0, xa1, true,  false);   // stages B(62) -> buf2
  BODY(61, 1, xb0, xb1, true,  false);   // stages B(63) -> buf0
  BODY(62, 2, xa0, xa1, false, false);   // 18 in flight -> vm9 drains t=62's
  BODY(63, 0, xb0, xb1, false, true);    // vm0
#undef BODY
#undef STAGE

  // epilogue: acc -> sC (overlays LDS; everything drained)
  __syncthreads();
  float (*sC)[CPD] = (float(*)[CPD])smem;
  #pragma unroll
  for (int mt = 0; mt < 2; ++mt) {
    #pragma unroll
    for (int j = 0; j < 3; ++j) {
      int col = wn * 48 + j * 16 + r;
      if (col < NCOL) {
        int row = wm * 32 + mt * 16 + kg * 4;
        sC[row + 0][col] = acc[mt][j][0];
        sC[row + 1][col] = acc[mt][j][1];
        sC[row + 2][col] = acc[mt][j][2];
        sC[row + 3][col] = acc[mt][j][3];
      }
    }
  }
  __syncthreads();

  // per-row sequential DAG: one lane per row
  if (tid < BM) {
    const int rr = tid;
    float Vm[NSLOT], Vs[NSLOT];
    #pragma unroll
    for (int i = 0; i < NSLOT; ++i) {
      float mv = sC[rr][i]      + b_init[i];
      float sv = sC[rr][16 + i] + b_init[16 + i];
      Vm[i] = fabsf(mv);
      Vs[i] = tanhf(sv);
    }
    float G[NSTEP];
    #pragma unroll
    for (int s = 0; s < NSTEP; ++s) {
      float gr = sC[rr][160 + s] + b_gate[s];
      G[s] = 1.0f / (1.0f + expf(-gr));
    }
    #pragma unroll
    for (int s = 0; s < NSTEP; ++s) {
      const float g = G[s];
      float R = 0.f, sp = 1.f;
      #pragma unroll
      for (int i = 0; i < NSLOT; ++i) {
        float Osi = (i < 8 + s) ? (sC[rr][32 + s * 16 + i] + b_op[s * 16 + i]) : 0.f;
        float sgn   = Vs[i] * Vm[i];
        float logm  = logf(fmaxf(Vm[i], 1e-12f));
        float mixed = logm * (1.f - g) + sgn * g;
        R  += Osi * mixed;
        sp *= Vs[i] * (fabsf(Osi) + 1.f);
      }
      float lin_sign = tanhf(R  / 1e-4f);
      float log_sign = tanhf(sp / 1e-4f);
      float vs_new = g * lin_sign + (1.f - g) * log_sign;
      float vm_new = g * fabsf(R) + (1.f - g) * expf(fminf(R, 23.026f));
      Vm[8 + s] = vm_new;
      Vs[8 + s] = vs_new;
    }
    out[row0 + rr] = Vs[NSLOT - 1] * Vm[NSLOT - 1];
  }
}

extern "C" void kernel_launch(void* const* d_in, const int* in_sizes, int n_in,
                              void* d_out, int out_size, void* d_ws, size_t ws_size,
                              hipStream_t stream) {
  (void)in_sizes; (void)n_in; (void)out_size; (void)ws_size;
  const float* hidden = (const float*)d_in[0];
  const float* W_init = (const float*)d_in[1];
  const float* b_init = (const float*)d_in[2];
  const float* W_op   = (const float*)d_in[3];
  const float* b_op   = (const float*)d_in[4];
  const float* W_gate = (const float*)d_in[5];
  const float* b_gate = (const float*)d_in[6];
  float* out = (float*)d_out;
  u32x4* wsB = (u32x4*)d_ws;      // 64 * 2112 * 16 B = 2.06 MiB

  prep_b<<<dim3(704), dim3(64), 0, stream>>>(W_init, W_op, W_gate, wsB);
  dag_main<<<dim3(NROW / BM), dim3(512), 0, stream>>>(hidden, wsB, b_init, b_op,
                                                      b_gate, out);
}